// Round 10
// baseline (2637.266 us; speedup 1.0000x reference)
//
#include <hip/hip_runtime.h>
#include <math.h>

// ============================ constants ============================
constexpr int NPTS = 32768;
constexpr long long SOFF = 33554432LL;        // NPTS*64*16, start of scalar outputs

// packed-weight offsets in d_ws (floats)
constexpr int OFF_GBW       = 0;        // [64c][3ch][128r][4]
constexpr int OFF_GBOW      = 98304;    // [64c][3ch][64o][4]
constexpr int OFF_L1W       = 147456;   // [64c][3ch][64o][4]
constexpr int OFF_L2W       = 196608;   // [64c][3ch][64o][4]
constexpr int OFF_GB_S2MV   = 245760;   // [32kq][128r][4]
constexpr int OFF_GBO_S2MV  = 262144;   // [32kq][64o][4]
constexpr int OFF_GBO_MVS2S = 270336;   // [16cq][256o][4]
constexpr int OFF_GBO_S2S   = 286720;   // [32kq][256o][4]
constexpr int OFF_L1_S2MV   = 319488;   // [64kq][64o][4]
constexpr int OFF_L1_MVS2S  = 335872;   // [16cq][256o][4]
constexpr int OFF_L1_S2S    = 352256;   // [64kq][256o][4]
constexpr int OFF_L2_S2MV   = 417792;   // [64kq][64o][4]
constexpr int OFF_L2_MVS2S  = 434176;   // [16cq][128o][4]
constexpr int OFF_L2_S2S    = 442368;   // [64kq][128o][4]
constexpr int W_TOTAL       = 475136;   // floats (~1.9MB)

// ==================== compile-time GA tables ====================
namespace ga {
constexpr int MASK_OF[16] = {0,1,2,4,8,3,5,9,6,10,12,7,11,13,14,15};
constexpr int idx_of_mask(int m){ int r = 0; for(int i=0;i<16;++i) if(MASK_OF[i]==m) r=i; return r; }
constexpr int pcount(int x){ int c=0; while(x){ c += x&1; x >>= 1; } return c; }
constexpr int nswaps(int a,int b){ int s=0; a >>= 1; while(a){ s += pcount(a&b); a >>= 1; } return s; }
constexpr float rsign(int a,int b){ return (nswaps(a,b)&1) ? -1.0f : 1.0f; }
constexpr float dsign(int m){ return rsign(m, 15^m); }
struct Ent { int i, j, k; float s; };
struct GPT { Ent e[192]; };
constexpr GPT make_gp(){
  GPT t{}; int n=0;
  for(int i=0;i<16;++i) for(int j=0;j<16;++j){
    const int a=MASK_OF[i], b=MASK_OF[j];
    if((a & b & 1) != 0) continue;             // e0^2 = 0
    t.e[n].i=i; t.e[n].j=j; t.e[n].k=idx_of_mask(a^b); t.e[n].s=rsign(a,b); ++n;
  }
  return t;
}
struct JNT { Ent e[81]; };
constexpr JNT make_jn(){
  JNT t{}; int n=0;
  for(int i=0;i<16;++i) for(int j=0;j<16;++j){
    const int ci = 15 ^ MASK_OF[i], cj = 15 ^ MASK_OF[j];
    if((ci & cj) != 0) continue;               // duals must be disjoint for wedge
    const int mr = ci ^ cj, mk = 15 ^ mr;
    t.e[n].i=i; t.e[n].j=j; t.e[n].k=idx_of_mask(mk);
    t.e[n].s = dsign(MASK_OF[i]) * dsign(MASK_OF[j]) * rsign(ci,cj) * dsign(mk);
    ++n;
  }
  return t;
}
constexpr GPT GPt = make_gp();
constexpr JNT JNt = make_jn();
} // namespace ga

// ============================ helpers ============================
__device__ __forceinline__ float dot4(float4 a, float4 b){
  return fmaf(a.x,b.x, fmaf(a.y,b.y, fmaf(a.z,b.z, a.w*b.w)));
}
__device__ __forceinline__ float gelu_t(float x){
  const float u = 0.7978845608028654f * x * (1.0f + 0.044715f * x * x);
  return 0.5f * x * (1.0f + tanhf(u));
}
__device__ __forceinline__ void accum_equi(float* __restrict__ a,
                                           const float* __restrict__ w,
                                           const float* __restrict__ x){
  a[0]  = fmaf(w[0],x[0],a[0]);
  a[1]  = fmaf(w[1],x[1],fmaf(w[5],x[0],a[1]));
  a[2]  = fmaf(w[1],x[2],a[2]);
  a[3]  = fmaf(w[1],x[3],a[3]);
  a[4]  = fmaf(w[1],x[4],a[4]);
  a[5]  = fmaf(w[2],x[5],fmaf(w[6],x[2],a[5]));
  a[6]  = fmaf(w[2],x[6],fmaf(w[6],x[3],a[6]));
  a[7]  = fmaf(w[2],x[7],fmaf(w[6],x[4],a[7]));
  a[8]  = fmaf(w[2],x[8],a[8]);
  a[9]  = fmaf(w[2],x[9],a[9]);
  a[10] = fmaf(w[2],x[10],a[10]);
  a[11] = fmaf(w[3],x[11],fmaf(w[7],x[8],a[11]));
  a[12] = fmaf(w[3],x[12],fmaf(w[7],x[9],a[12]));
  a[13] = fmaf(w[3],x[13],fmaf(w[7],x[10],a[13]));
  a[14] = fmaf(w[3],x[14],a[14]);
  a[15] = fmaf(w[4],x[15],fmaf(w[8],x[14],a[15]));
}
__device__ __forceinline__ void ld16(const float* __restrict__ p, float* __restrict__ x){
  const float4 a=*(const float4*)p, b=*(const float4*)(p+4), c=*(const float4*)(p+8), d=*(const float4*)(p+12);
  x[0]=a.x; x[1]=a.y; x[2]=a.z; x[3]=a.w; x[4]=b.x; x[5]=b.y; x[6]=b.z; x[7]=b.w;
  x[8]=c.x; x[9]=c.y; x[10]=c.z; x[11]=c.w; x[12]=d.x; x[13]=d.y; x[14]=d.z; x[15]=d.w;
}
__device__ __forceinline__ void st16(float* __restrict__ p, const float* __restrict__ x){
  *(float4*)(p)    = make_float4(x[0],x[1],x[2],x[3]);
  *(float4*)(p+4)  = make_float4(x[4],x[5],x[6],x[7]);
  *(float4*)(p+8)  = make_float4(x[8],x[9],x[10],x[11]);
  *(float4*)(p+12) = make_float4(x[12],x[13],x[14],x[15]);
}

// ======================= weight repack kernel (unchanged) =======================
__global__ void prep_pack(
    const float* __restrict__ gb_w_mv,   const float* __restrict__ gb_w_s2mv,
    const float* __restrict__ gbo_w_mv,  const float* __restrict__ gbo_w_s2mv,
    const float* __restrict__ gbo_w_mvs2s, const float* __restrict__ gbo_w_s2s,
    const float* __restrict__ l1_w_mv,   const float* __restrict__ l1_w_s2mv,
    const float* __restrict__ l1_w_mvs2s, const float* __restrict__ l1_w_s2s,
    const float* __restrict__ l2_w_mv,   const float* __restrict__ l2_w_s2mv,
    const float* __restrict__ l2_w_mvs2s, const float* __restrict__ l2_w_s2s,
    float* __restrict__ W)
{
  const int idx = blockIdx.x * 256 + threadIdx.x;
  if (idx >= W_TOTAL) return;
  float v = 0.0f;
  if (idx < OFF_GBOW) {
    const int l=idx, j=l&3, t=l>>2, r=t&127, t2=t>>7, ch=t2%3, c=t2/3, k=ch*4+j;
    if (k < 9) v = gb_w_mv[(r*64 + c)*9 + k];
  } else if (idx < OFF_L1W) {
    const int l=idx-OFF_GBOW, j=l&3, t=l>>2, o=t&63, t2=t>>6, ch=t2%3, c=t2/3, k=ch*4+j;
    if (k < 9) v = gbo_w_mv[(o*64 + c)*9 + k];
  } else if (idx < OFF_L2W) {
    const int l=idx-OFF_L1W, j=l&3, t=l>>2, o=t&63, t2=t>>6, ch=t2%3, c=t2/3, k=ch*4+j;
    if (k < 9) v = l1_w_mv[(o*64 + c)*9 + k];
  } else if (idx < OFF_GB_S2MV) {
    const int l=idx-OFF_L2W, j=l&3, t=l>>2, o=t&63, t2=t>>6, ch=t2%3, c=t2/3, k=ch*4+j;
    if (k < 9) v = l2_w_mv[(o*64 + c)*9 + k];
  } else if (idx < OFF_GBO_S2MV) {
    const int l=idx-OFF_GB_S2MV, j=l&3, t=l>>2, r=t&127, kq=t>>7;
    v = gb_w_s2mv[r*128 + kq*4 + j];
  } else if (idx < OFF_GBO_MVS2S) {
    const int l=idx-OFF_GBO_S2MV, j=l&3, t=l>>2, o=t&63, kq=t>>6;
    v = gbo_w_s2mv[o*128 + kq*4 + j];
  } else if (idx < OFF_GBO_S2S) {
    const int l=idx-OFF_GBO_MVS2S, j=l&3, t=l>>2, o=t&255, cq=t>>8;
    v = gbo_w_mvs2s[o*64 + cq*4 + j];
  } else if (idx < OFF_L1_S2MV) {
    const int l=idx-OFF_GBO_S2S, j=l&3, t=l>>2, o=t&255, kq=t>>8;
    v = gbo_w_s2s[o*128 + kq*4 + j];
  } else if (idx < OFF_L1_MVS2S) {
    const int l=idx-OFF_L1_S2MV, j=l&3, t=l>>2, o=t&63, kq=t>>6;
    v = l1_w_s2mv[o*256 + kq*4 + j];
  } else if (idx < OFF_L1_S2S) {
    const int l=idx-OFF_L1_MVS2S, j=l&3, t=l>>2, o=t&255, cq=t>>8;
    v = l1_w_mvs2s[o*64 + cq*4 + j];
  } else if (idx < OFF_L2_S2MV) {
    const int l=idx-OFF_L1_S2S, j=l&3, t=l>>2, o=t&255, kq=t>>8;
    v = l1_w_s2s[o*256 + kq*4 + j];
  } else if (idx < OFF_L2_MVS2S) {
    const int l=idx-OFF_L2_S2MV, j=l&3, t=l>>2, o=t&63, kq=t>>6;
    v = l2_w_s2mv[o*256 + kq*4 + j];
  } else if (idx < OFF_L2_S2S) {
    const int l=idx-OFF_L2_MVS2S, j=l&3, t=l>>2, o=t&127, cq=t>>7;
    v = l2_w_mvs2s[o*64 + cq*4 + j];
  } else {
    const int l=idx-OFF_L2_S2S, j=l&3, t=l>>2, o=t&127, kq=t>>7;
    v = l2_w_s2s[o*256 + kq*4 + j];
  }
  W[idx] = v;
}

// ======================= Kernel A (unchanged from R6) =======================
__global__ __launch_bounds__(256, 1) void stage_a(
    const float* __restrict__ xin, const float* __restrict__ sinp,
    const float* __restrict__ gb_b_mv, const float* __restrict__ W,
    float* __restrict__ hid)
{
  __shared__ float smem[16384];
  const int tid = threadIdx.x;
  const int n0  = blockIdx.x * 8;
  {
    const float4* src = (const float4*)(xin + (size_t)n0 * 1024);
    float4* dst = (float4*)smem;
    #pragma unroll
    for (int q = 0; q < 8; ++q) dst[q * 256 + tid] = src[q * 256 + tid];
    ((float4*)(smem + 8192))[tid] = ((const float4*)(sinp + (size_t)n0 * 128))[tid];
  }
  __syncthreads();
  const int r  = tid & 127;
  const int pg = tid >> 7;
  float acc[4][16];
  #pragma unroll
  for (int i = 0; i < 4; ++i)
    #pragma unroll
    for (int j = 0; j < 16; ++j) acc[i][j] = 0.0f;
  const float* Wg = W + OFF_GBW;
  const float* xp = smem + pg * 4096;
  for (int c = 0; c < 64; ++c) {
    const float4 wa = *(const float4*)(Wg + (((c*3+0)<<7) + r)*4);
    const float4 wb = *(const float4*)(Wg + (((c*3+1)<<7) + r)*4);
    const float4 wc = *(const float4*)(Wg + (((c*3+2)<<7) + r)*4);
    const float w12[12] = {wa.x,wa.y,wa.z,wa.w, wb.x,wb.y,wb.z,wb.w, wc.x,wc.y,wc.z,wc.w};
    #pragma unroll
    for (int i = 0; i < 4; ++i) {
      float xv[16];
      ld16(xp + i*1024 + c*16, xv);
      accum_equi(acc[i], w12, xv);
    }
  }
  {
    const float* Ws = W + OFF_GB_S2MV;
    const float* sp = smem + 8192 + pg * 512;
    for (int kq = 0; kq < 32; ++kq) {
      const float4 wq = *(const float4*)(Ws + ((kq<<7) + r)*4);
      #pragma unroll
      for (int i = 0; i < 4; ++i) {
        const float4 sv = *(const float4*)(sp + i*128 + (kq<<2));
        acc[i][0] += dot4(wq, sv);
      }
    }
    const float bias = gb_b_mv[r];
    #pragma unroll
    for (int i = 0; i < 4; ++i) acc[i][0] += bias;
  }
  __syncthreads();
  #pragma unroll
  for (int i = 0; i < 4; ++i)
    st16(smem + ((pg*4 + i)*128 + r)*16, acc[i]);
  __syncthreads();
  {
    const int h  = tid & 31;
    const int pp = tid >> 5;
    float L[16], R[16], o16[16];
    ld16(smem + (pp*128 + h)*16, L);
    ld16(smem + (pp*128 + 32 + h)*16, R);
    #pragma unroll
    for (int j = 0; j < 16; ++j) o16[j] = 0.0f;
    #pragma unroll
    for (int n = 0; n < 192; ++n)
      o16[ga::GPt.e[n].k] = fmaf(ga::GPt.e[n].s * L[ga::GPt.e[n].i], R[ga::GPt.e[n].j], o16[ga::GPt.e[n].k]);
    st16(hid + (((size_t)(n0 + pp) * 64) + h) * 16, o16);
    ld16(smem + (pp*128 + 64 + h)*16, L);
    ld16(smem + (pp*128 + 96 + h)*16, R);
    #pragma unroll
    for (int j = 0; j < 16; ++j) o16[j] = 0.0f;
    #pragma unroll
    for (int n = 0; n < 81; ++n)
      o16[ga::JNt.e[n].k] = fmaf(ga::JNt.e[n].s * L[ga::JNt.e[n].i], R[ga::JNt.e[n].j], o16[ga::JNt.e[n].k]);
    st16(hid + (((size_t)(n0 + pp) * 64) + 32 + h) * 16, o16);
  }
}

// ================= bcd v10: blade-halves across 8 waves, 4 points =================
// 512 threads, 4 points. Wave wv: p = wv&3, half h = wv>>2 -> blades 8h..8h+7
// of point p. acc[8]/thread (~60-80 live regs) -> cap 128 via (512,2) ->
// 4 waves/SIMD. Scalar role: thread = (row = tid&255, h = tid>>8) -> points
// {2h, 2h+1}, sacc[2]. Norms: lane shfl-reduce + tiny-LDS cross-wave combine.
__global__ __launch_bounds__(512, 2) void bcd(
    const float* __restrict__ sinp,
    const float* __restrict__ gbo_b_mv, const float* __restrict__ gbo_b_s,
    const float* __restrict__ l1_b_mv,  const float* __restrict__ l1_b_s,
    const float* __restrict__ l2_b_mv,  const float* __restrict__ l2_b_s,
    const float* __restrict__ W,
    float* __restrict__ out)           // hid lives in out's mv region
{
  __shared__ float hidt[4][64][16];  // 16 KB (reads are wave-uniform broadcasts)
  __shared__ float s1b[4][256];      // 4 KB
  __shared__ float s2b[4][256];      // 4 KB
  __shared__ float sin_[4][128];     // 2 KB
  __shared__ float c0t[4][64];       // 1 KB  comp-0 of current mv input
  __shared__ float gatet[4][64];     // 1 KB  gate broadcast
  __shared__ float red_eq[8];        // equi-norm wave partials
  __shared__ float red_s[8][2];      // scalar-norm sum partials
  __shared__ float red_q[8][2];      // scalar-norm ssq partials

  const int tid  = threadIdx.x;
  const int o    = tid & 63;
  const int wv   = tid >> 6;         // 0..7
  const int p    = wv & 3;           // mv-role point
  const int h    = wv >> 2;          // blade half (== tid>>8, scalar-role group)
  const int srow = tid & 255;        // scalar-role row
  const int n0   = blockIdx.x * 4;

  { // stage hid tile (1024 float4) + comp0 + sinp
    const float4* hsrc = (const float4*)(out + (size_t)n0 * 1024);
    float4* hdst = (float4*)&hidt[0][0][0];
    #pragma unroll
    for (int q = 0; q < 2; ++q) {
      const int i = q * 512 + tid;
      const float4 v = hsrc[i];
      hdst[i] = v;
      if ((i & 3) == 0) c0t[i >> 8][(i >> 2) & 63] = v.x;
    }
    if (tid < 128) ((float4*)&sin_[0][0])[tid] = ((const float4*)(sinp + (size_t)n0 * 128))[tid];
  }
  __syncthreads();

  // ======================= stages B and C =======================
  #pragma unroll 1
  for (int stage = 0; stage < 2; ++stage) {
    const int offMV    = stage == 0 ? OFF_GBOW      : OFF_L1W;
    const int offS2MV  = stage == 0 ? OFF_GBO_S2MV  : OFF_L1_S2MV;
    const int offS2S   = stage == 0 ? OFF_GBO_S2S   : OFF_L1_S2S;
    const int offMVS2S = stage == 0 ? OFF_GBO_MVS2S : OFF_L1_MVS2S;
    const int nkq      = stage == 0 ? 32 : 64;
    const float* b_mv  = stage == 0 ? gbo_b_mv : l1_b_mv;
    const float* b_s   = stage == 0 ? gbo_b_s  : l1_b_s;
    const float* ssrc  = stage == 0 ? &sin_[0][0] : &s1b[0][0];
    const int    sstr  = stage == 0 ? 128 : 256;
    float* sdst        = stage == 0 ? &s1b[0][0] : &s2b[0][0];

    // ---- mv role: blades 8h..8h+7 of point p ----
    float acc[8];
    #pragma unroll
    for (int j = 0; j < 8; ++j) acc[j] = 0.0f;
    const float* Wg = W + offMV;
    if (h == 0) {
      for (int c = 0; c < 64; ++c) {
        const float4 wA = *(const float4*)(Wg + (((c*3+0)<<6) + o)*4);  // w0..3
        const float4 wB = *(const float4*)(Wg + (((c*3+1)<<6) + o)*4);  // w4..7
        const float* xr = &hidt[p][c][0];
        const float4 x0 = *(const float4*)(xr), x1 = *(const float4*)(xr + 4);
        acc[0] = fmaf(wA.x, x0.x, acc[0]);                         // j0 = w0*x0
        acc[1] = fmaf(wA.y, x0.y, fmaf(wB.y, x0.x, acc[1]));       // j1 = w1*x1 + w5*x0
        acc[2] = fmaf(wA.y, x0.z, acc[2]);                         // j2 = w1*x2
        acc[3] = fmaf(wA.y, x0.w, acc[3]);                         // j3 = w1*x3
        acc[4] = fmaf(wA.y, x1.x, acc[4]);                         // j4 = w1*x4
        acc[5] = fmaf(wA.z, x1.y, fmaf(wB.z, x0.z, acc[5]));       // j5 = w2*x5 + w6*x2
        acc[6] = fmaf(wA.z, x1.z, fmaf(wB.z, x0.w, acc[6]));       // j6 = w2*x6 + w6*x3
        acc[7] = fmaf(wA.z, x1.w, fmaf(wB.z, x1.x, acc[7]));       // j7 = w2*x7 + w6*x4
      }
      // scalars -> comp0 + bias (blade 0 lives in half 0)
      for (int kq = 0; kq < nkq; ++kq) {
        const float4 wq = *(const float4*)(W + offS2MV + (((kq<<6) + o)<<2));
        acc[0] += dot4(wq, *(const float4*)(ssrc + p*sstr + (kq<<2)));
      }
      acc[0] += b_mv[o];
    } else {
      for (int c = 0; c < 64; ++c) {
        const float4 wA = *(const float4*)(Wg + (((c*3+0)<<6) + o)*4);
        const float4 wB = *(const float4*)(Wg + (((c*3+1)<<6) + o)*4);
        const float w8 = Wg[(((c*3+2)<<6) + o)*4];
        const float* xr = &hidt[p][c][8];
        const float4 x2 = *(const float4*)(xr), x3 = *(const float4*)(xr + 4);
        acc[0] = fmaf(wA.z, x2.x, acc[0]);                         // j8  = w2*x8
        acc[1] = fmaf(wA.z, x2.y, acc[1]);                         // j9  = w2*x9
        acc[2] = fmaf(wA.z, x2.z, acc[2]);                         // j10 = w2*x10
        acc[3] = fmaf(wA.w, x2.w, fmaf(wB.w, x2.x, acc[3]));       // j11 = w3*x11 + w7*x8
        acc[4] = fmaf(wA.w, x3.x, fmaf(wB.w, x2.y, acc[4]));       // j12 = w3*x12 + w7*x9
        acc[5] = fmaf(wA.w, x3.y, fmaf(wB.w, x2.z, acc[5]));       // j13 = w3*x13 + w7*x10
        acc[6] = fmaf(wA.w, x3.z, acc[6]);                         // j14 = w3*x14
        acc[7] = fmaf(wB.x, x3.w, fmaf(w8, x3.z, acc[7]));         // j15 = w4*x15 + w8*x14
      }
    }

    // ---- scalar role: rows 0..255, points {2h, 2h+1} ----
    float sacc[2] = {0.f, 0.f};
    for (int kq = 0; kq < nkq; ++kq) {
      const float4 ws = *(const float4*)(W + offS2S + (((kq<<8) + srow)<<2));
      sacc[0] += dot4(ws, *(const float4*)(ssrc + (2*h+0)*sstr + (kq<<2)));
      sacc[1] += dot4(ws, *(const float4*)(ssrc + (2*h+1)*sstr + (kq<<2)));
    }
    for (int cq = 0; cq < 16; ++cq) {
      const float4 wq = *(const float4*)(W + offMVS2S + (((cq<<8) + srow)<<2));
      sacc[0] += dot4(wq, *(const float4*)(&c0t[2*h+0][cq<<2]));
      sacc[1] += dot4(wq, *(const float4*)(&c0t[2*h+1][cq<<2]));
    }
    {
      const float bs = b_s[srow];
      sacc[0] += bs; sacc[1] += bs;
    }

    // ---- norm partials ----
    // INNER = {0,2,3,4, 8,9,10,14}: half0 local {0,2,3,4}; half1 local {0,1,2,6}
    float peq = (h == 0)
        ? acc[0]*acc[0] + acc[2]*acc[2] + acc[3]*acc[3] + acc[4]*acc[4]
        : acc[0]*acc[0] + acc[1]*acc[1] + acc[2]*acc[2] + acc[6]*acc[6];
    float ps0 = sacc[0], ps1 = sacc[1];
    float pq0 = sacc[0]*sacc[0], pq1 = sacc[1]*sacc[1];
    #pragma unroll
    for (int m = 1; m < 64; m <<= 1) {
      peq += __shfl_xor(peq, m);
      ps0 += __shfl_xor(ps0, m); ps1 += __shfl_xor(ps1, m);
      pq0 += __shfl_xor(pq0, m); pq1 += __shfl_xor(pq1, m);
    }
    if (o == 0) {
      red_eq[wv]   = peq;
      red_s[wv][0] = ps0; red_s[wv][1] = ps1;
      red_q[wv][0] = pq0; red_q[wv][1] = pq1;
    }
    __syncthreads();

    // equi-norm scale for my mv point p
    const float rs = 1.0f / sqrtf(fmaxf((red_eq[p] + red_eq[4+p]) * (1.0f/64.0f), 0.01f));
    // scalar norms for my scalar points {2h, 2h+1}
    {
      const int base = 4*h;
      #pragma unroll
      for (int i = 0; i < 2; ++i) {
        const float sum = red_s[base+0][i] + red_s[base+1][i] + red_s[base+2][i] + red_s[base+3][i];
        const float ssq = red_q[base+0][i] + red_q[base+1][i] + red_q[base+2][i] + red_q[base+3][i];
        const float mu   = sum * (1.0f/256.0f);
        const float var  = ssq * (1.0f/256.0f) - mu*mu;
        const float rstd = rsqrtf(var + 1e-5f);
        sdst[(2*h+i)*256 + srow] = gelu_t((sacc[i] - mu) * rstd);
      }
    }
    if (h == 0) { // gate + new comp0 (blade 0)
      const float a0n = acc[0] * rs;
      const float g   = gelu_t(a0n);
      gatet[p][o] = g;
      c0t[p][o]   = g * a0n;
    }
    __syncthreads();

    { // write gated mv back to hidt (each wave writes its half)
      const float f = rs * gatet[p][o];
      float* dst = &hidt[p][o][h*8];
      *(float4*)(dst)     = make_float4(acc[0]*f, acc[1]*f, acc[2]*f, acc[3]*f);
      *(float4*)(dst + 4) = make_float4(acc[4]*f, acc[5]*f, acc[6]*f, acc[7]*f);
    }
    __syncthreads();
  }

  // ======================= stage D: l2 (plain) -> global =======================
  {
    float acc[8];
    #pragma unroll
    for (int j = 0; j < 8; ++j) acc[j] = 0.0f;
    const float* Wg = W + OFF_L2W;
    if (h == 0) {
      for (int c = 0; c < 64; ++c) {
        const float4 wA = *(const float4*)(Wg + (((c*3+0)<<6) + o)*4);
        const float4 wB = *(const float4*)(Wg + (((c*3+1)<<6) + o)*4);
        const float* xr = &hidt[p][c][0];
        const float4 x0 = *(const float4*)(xr), x1 = *(const float4*)(xr + 4);
        acc[0] = fmaf(wA.x, x0.x, acc[0]);
        acc[1] = fmaf(wA.y, x0.y, fmaf(wB.y, x0.x, acc[1]));
        acc[2] = fmaf(wA.y, x0.z, acc[2]);
        acc[3] = fmaf(wA.y, x0.w, acc[3]);
        acc[4] = fmaf(wA.y, x1.x, acc[4]);
        acc[5] = fmaf(wA.z, x1.y, fmaf(wB.z, x0.z, acc[5]));
        acc[6] = fmaf(wA.z, x1.z, fmaf(wB.z, x0.w, acc[6]));
        acc[7] = fmaf(wA.z, x1.w, fmaf(wB.z, x1.x, acc[7]));
      }
      for (int kq = 0; kq < 64; ++kq) {
        const float4 wq = *(const float4*)(W + OFF_L2_S2MV + (((kq<<6) + o)<<2));
        acc[0] += dot4(wq, *(const float4*)(&s2b[p][kq<<2]));
      }
      acc[0] += l2_b_mv[o];
    } else {
      for (int c = 0; c < 64; ++c) {
        const float4 wA = *(const float4*)(Wg + (((c*3+0)<<6) + o)*4);
        const float4 wB = *(const float4*)(Wg + (((c*3+1)<<6) + o)*4);
        const float w8 = Wg[(((c*3+2)<<6) + o)*4];
        const float* xr = &hidt[p][c][8];
        const float4 x2 = *(const float4*)(xr), x3 = *(const float4*)(xr + 4);
        acc[0] = fmaf(wA.z, x2.x, acc[0]);
        acc[1] = fmaf(wA.z, x2.y, acc[1]);
        acc[2] = fmaf(wA.z, x2.z, acc[2]);
        acc[3] = fmaf(wA.w, x2.w, fmaf(wB.w, x2.x, acc[3]));
        acc[4] = fmaf(wA.w, x3.x, fmaf(wB.w, x2.y, acc[4]));
        acc[5] = fmaf(wA.w, x3.y, fmaf(wB.w, x2.z, acc[5]));
        acc[6] = fmaf(wA.w, x3.z, acc[6]);
        acc[7] = fmaf(wB.x, x3.w, fmaf(w8, x3.z, acc[7]));
      }
    }
    { // mv output (each wave writes its half)
      float* dst = out + ((size_t)(n0 + p)*64 + o)*16 + h*8;
      *(float4*)(dst)     = make_float4(acc[0], acc[1], acc[2], acc[3]);
      *(float4*)(dst + 4) = make_float4(acc[4], acc[5], acc[6], acc[7]);
    }
    // scalar role: row = tid&127, point grp = tid>>7 (wave-uniform)
    {
      const int row = tid & 127;
      const int grp = tid >> 7;
      float sd = 0.0f;
      for (int kq = 0; kq < 64; ++kq) {
        const float4 ws = *(const float4*)(W + OFF_L2_S2S + (((kq<<7) + row)<<2));
        sd += dot4(ws, *(const float4*)(&s2b[grp][kq<<2]));
      }
      for (int cq = 0; cq < 16; ++cq) {
        const float4 wq = *(const float4*)(W + OFF_L2_MVS2S + (((cq<<7) + row)<<2));
        sd += dot4(wq, *(const float4*)(&c0t[grp][cq<<2]));
      }
      out[SOFF + (size_t)(n0 + grp)*128 + row] = sd + l2_b_s[row];
    }
  }
}

// ============================ host launch ============================
extern "C" void kernel_launch(void* const* d_in, const int* in_sizes, int n_in,
                              void* d_out, int out_size, void* d_ws, size_t ws_size,
                              hipStream_t stream) {
  const float* xin          = (const float*)d_in[0];
  const float* sinp         = (const float*)d_in[1];
  const float* gb_w_mv      = (const float*)d_in[2];
  const float* gb_w_s2mv    = (const float*)d_in[3];
  const float* gb_b_mv      = (const float*)d_in[4];
  const float* gbo_w_mv     = (const float*)d_in[5];
  const float* gbo_w_s2mv   = (const float*)d_in[6];
  const float* gbo_b_mv     = (const float*)d_in[7];
  const float* gbo_w_mvs2s  = (const float*)d_in[8];
  const float* gbo_w_s2s    = (const float*)d_in[9];
  const float* gbo_b_s      = (const float*)d_in[10];
  const float* l1_w_mv      = (const float*)d_in[11];
  const float* l1_w_s2mv    = (const float*)d_in[12];
  const float* l1_b_mv      = (const float*)d_in[13];
  const float* l1_w_mvs2s   = (const float*)d_in[14];
  const float* l1_w_s2s     = (const float*)d_in[15];
  const float* l1_b_s       = (const float*)d_in[16];
  const float* l2_w_mv      = (const float*)d_in[17];
  const float* l2_w_s2mv    = (const float*)d_in[18];
  const float* l2_b_mv      = (const float*)d_in[19];
  const float* l2_w_mvs2s   = (const float*)d_in[20];
  const float* l2_w_s2s     = (const float*)d_in[21];
  const float* l2_b_s       = (const float*)d_in[22];
  float* W   = (float*)d_ws;
  float* out = (float*)d_out;

  prep_pack<<<(W_TOTAL + 255) / 256, 256, 0, stream>>>(
      gb_w_mv, gb_w_s2mv, gbo_w_mv, gbo_w_s2mv, gbo_w_mvs2s, gbo_w_s2s,
      l1_w_mv, l1_w_s2mv, l1_w_mvs2s, l1_w_s2s,
      l2_w_mv, l2_w_s2mv, l2_w_mvs2s, l2_w_s2s, W);

  stage_a<<<NPTS / 8, 256, 0, stream>>>(xin, sinp, gb_b_mv, W, out);

  bcd<<<NPTS / 4, 512, 0, stream>>>(
      sinp, gbo_b_mv, gbo_b_s, l1_b_mv, l1_b_s, l2_b_mv, l2_b_s, W, out);
}

// Round 11
// 981.894 us; speedup vs baseline: 2.6859x; 2.6859x over previous
//
#include <hip/hip_runtime.h>
#include <math.h>

typedef __bf16 bf16x8 __attribute__((ext_vector_type(8)));
typedef float  f32x4  __attribute__((ext_vector_type(4)));

// ============================ constants ============================
constexpr int NPTS = 32768;
constexpr long long SOFF = 33554432LL;        // NPTS*64*16, start of scalar outputs

// ---- fp32 weight region (stage_a) in d_ws, float offsets ----
constexpr int OFF_GBW     = 0;        // [64c][3ch][128r][4]
constexpr int OFF_GB_S2MV = 98304;    // [32kq][128r][4]
constexpr int FP_TOTAL    = 114688;   // floats (448KB)

// ---- bf16 fragment region (bcdm), element offsets; hi at [0,TOT), lo at [TOT,2TOT) ----
constexpr int TOT_BF   = 323584;
constexpr int FB_MVB    = 0;        // [9k][4nt][2ks][64l][8e] = 36864
constexpr int FB_MVC    = 36864;
constexpr int FB_MVD    = 73728;
constexpr int FB_S2MV_B = 110592;   // [4nt][4ks][64][8] = 8192   (K=128)
constexpr int FB_S2MV_C = 118784;   // [4nt][8ks][64][8] = 16384  (K=256)
constexpr int FB_S2MV_D = 135168;   // 16384
constexpr int FB_S2S_B  = 151552;   // [16nt][4ks][64][8] = 32768
constexpr int FB_S2S_C  = 184320;   // [16nt][8ks][64][8] = 65536
constexpr int FB_S2S_D  = 249856;   // [8nt][8ks][64][8]  = 32768
constexpr int FB_MS2S_B = 282624;   // [16nt][2ks][64][8] = 16384
constexpr int FB_MS2S_C = 299008;   // 16384
constexpr int FB_MS2S_D = 315392;   // [8nt][2ks][64][8]  = 8192 -> 323584

// ---- bcdm LDS layout (bytes) ----
constexpr int XA_OFF = 0;        // bf16 [16j][16p][64c] swizzled, 32768
constexpr int SA_OFF = 32768;    // bf16 [16p][128] swizzled, 4096
constexpr int T1_OFF = 36864;    // bf16 [16p][256] swizzled, 8192
constexpr int T2_OFF = 45056;    // 8192
constexpr int C0_OFF = 53248;    // bf16 [16p][64] swizzled, 2048
constexpr int RED_OFF = 55296;   // 3 x float[64]
constexpr int LDS_BYTES = 56320;

// ==================== compile-time GA tables (stage_a) ====================
namespace ga {
constexpr int MASK_OF[16] = {0,1,2,4,8,3,5,9,6,10,12,7,11,13,14,15};
constexpr int idx_of_mask(int m){ int r = 0; for(int i=0;i<16;++i) if(MASK_OF[i]==m) r=i; return r; }
constexpr int pcount(int x){ int c=0; while(x){ c += x&1; x >>= 1; } return c; }
constexpr int nswaps(int a,int b){ int s=0; a >>= 1; while(a){ s += pcount(a&b); a >>= 1; } return s; }
constexpr float rsign(int a,int b){ return (nswaps(a,b)&1) ? -1.0f : 1.0f; }
constexpr float dsign(int m){ return rsign(m, 15^m); }
struct Ent { int i, j, k; float s; };
struct GPT { Ent e[192]; };
constexpr GPT make_gp(){
  GPT t{}; int n=0;
  for(int i=0;i<16;++i) for(int j=0;j<16;++j){
    const int a=MASK_OF[i], b=MASK_OF[j];
    if((a & b & 1) != 0) continue;
    t.e[n].i=i; t.e[n].j=j; t.e[n].k=idx_of_mask(a^b); t.e[n].s=rsign(a,b); ++n;
  }
  return t;
}
struct JNT { Ent e[81]; };
constexpr JNT make_jn(){
  JNT t{}; int n=0;
  for(int i=0;i<16;++i) for(int j=0;j<16;++j){
    const int ci = 15 ^ MASK_OF[i], cj = 15 ^ MASK_OF[j];
    if((ci & cj) != 0) continue;
    const int mr = ci ^ cj, mk = 15 ^ mr;
    t.e[n].i=i; t.e[n].j=j; t.e[n].k=idx_of_mask(mk);
    t.e[n].s = dsign(MASK_OF[i]) * dsign(MASK_OF[j]) * rsign(ci,cj) * dsign(mk);
    ++n;
  }
  return t;
}
constexpr GPT GPt = make_gp();
constexpr JNT JNt = make_jn();
} // namespace ga

// ============================ helpers ============================
__device__ __forceinline__ float dot4(float4 a, float4 b){
  return fmaf(a.x,b.x, fmaf(a.y,b.y, fmaf(a.z,b.z, a.w*b.w)));
}
__device__ __forceinline__ float gelu_t(float x){
  const float u = 0.7978845608028654f * x * (1.0f + 0.044715f * x * x);
  return 0.5f * x * (1.0f + tanhf(u));
}
__device__ __forceinline__ void accum_equi(float* __restrict__ a,
                                           const float* __restrict__ w,
                                           const float* __restrict__ x){
  a[0]  = fmaf(w[0],x[0],a[0]);
  a[1]  = fmaf(w[1],x[1],fmaf(w[5],x[0],a[1]));
  a[2]  = fmaf(w[1],x[2],a[2]);
  a[3]  = fmaf(w[1],x[3],a[3]);
  a[4]  = fmaf(w[1],x[4],a[4]);
  a[5]  = fmaf(w[2],x[5],fmaf(w[6],x[2],a[5]));
  a[6]  = fmaf(w[2],x[6],fmaf(w[6],x[3],a[6]));
  a[7]  = fmaf(w[2],x[7],fmaf(w[6],x[4],a[7]));
  a[8]  = fmaf(w[2],x[8],a[8]);
  a[9]  = fmaf(w[2],x[9],a[9]);
  a[10] = fmaf(w[2],x[10],a[10]);
  a[11] = fmaf(w[3],x[11],fmaf(w[7],x[8],a[11]));
  a[12] = fmaf(w[3],x[12],fmaf(w[7],x[9],a[12]));
  a[13] = fmaf(w[3],x[13],fmaf(w[7],x[10],a[13]));
  a[14] = fmaf(w[3],x[14],a[14]);
  a[15] = fmaf(w[4],x[15],fmaf(w[8],x[14],a[15]));
}
__device__ __forceinline__ void ld16(const float* __restrict__ p, float* __restrict__ x){
  const float4 a=*(const float4*)p, b=*(const float4*)(p+4), c=*(const float4*)(p+8), d=*(const float4*)(p+12);
  x[0]=a.x; x[1]=a.y; x[2]=a.z; x[3]=a.w; x[4]=b.x; x[5]=b.y; x[6]=b.z; x[7]=b.w;
  x[8]=c.x; x[9]=c.y; x[10]=c.z; x[11]=c.w; x[12]=d.x; x[13]=d.y; x[14]=d.z; x[15]=d.w;
}
__device__ __forceinline__ void st16(float* __restrict__ p, const float* __restrict__ x){
  *(float4*)(p)    = make_float4(x[0],x[1],x[2],x[3]);
  *(float4*)(p+4)  = make_float4(x[4],x[5],x[6],x[7]);
  *(float4*)(p+8)  = make_float4(x[8],x[9],x[10],x[11]);
  *(float4*)(p+12) = make_float4(x[12],x[13],x[14],x[15]);
}
__device__ __forceinline__ int swz(int p, int byteoff){ return byteoff ^ ((p & 7) << 4); }

// ======================= prep: fp32 stage_a weights =======================
__global__ void prep_fp(const float* __restrict__ gb_w_mv,
                        const float* __restrict__ gb_w_s2mv,
                        float* __restrict__ W)
{
  const int idx = blockIdx.x * 256 + threadIdx.x;
  if (idx >= FP_TOTAL) return;
  float v = 0.0f;
  if (idx < OFF_GB_S2MV) {                     // gb_w_mv [4,32,64,9] -> [c][ch][128r][4]
    const int j=idx&3, t=idx>>2, r=t&127, t2=t>>7, ch=t2%3, c=t2/3, k=ch*4+j;
    if (k < 9) v = gb_w_mv[(r*64 + c)*9 + k];
  } else {                                     // gb_w_s2mv [128r][128k] -> [kq][128r][4]
    const int l=idx-OFF_GB_S2MV, j=l&3, t=l>>2, r=t&127, kq=t>>7;
    v = gb_w_s2mv[r*128 + kq*4 + j];
  }
  W[idx] = v;
}

// ======================= prep: bf16 fragment weights (hi+lo) =======================
// Fragment layout per matrix: [nt][ks][lane][8e], element (o = 16*nt + (l&15),
// k = 32*ks + 8*(l>>4) + e). B-operand of mfma_f32_16x16x32_bf16.
__global__ void prep_bf(
    const float* __restrict__ gbo_w_mv, const float* __restrict__ gbo_w_s2mv,
    const float* __restrict__ gbo_w_mvs2s, const float* __restrict__ gbo_w_s2s,
    const float* __restrict__ l1_w_mv, const float* __restrict__ l1_w_s2mv,
    const float* __restrict__ l1_w_mvs2s, const float* __restrict__ l1_w_s2s,
    const float* __restrict__ l2_w_mv, const float* __restrict__ l2_w_s2mv,
    const float* __restrict__ l2_w_mvs2s, const float* __restrict__ l2_w_s2s,
    unsigned short* __restrict__ WBu)
{
  const int idx = blockIdx.x * 256 + threadIdx.x;
  if (idx >= TOT_BF) return;
  float v = 0.0f;
  if (idx < FB_S2MV_B) {                       // mv: [st][9k][4nt][2ks][64][8]
    const int st = idx / 36864, r2 = idx % 36864;
    const int k9 = r2 >> 12, r3 = r2 & 4095;
    const int nt = r3 >> 10, ks = (r3 >> 9) & 1, l = (r3 >> 3) & 63, e = r3 & 7;
    const int o = 16*nt + (l & 15), c = 32*ks + 8*(l >> 4) + e;
    const float* src = st==0 ? gbo_w_mv : (st==1 ? l1_w_mv : l2_w_mv);
    v = src[(o*64 + c)*9 + k9];
  } else if (idx < FB_S2S_B) {                 // s2mv  [64o x K]
    const float* src; int r, KS, KK;
    if (idx < FB_S2MV_C)      { r = idx - FB_S2MV_B; KS=4; KK=128; src=gbo_w_s2mv; }
    else if (idx < FB_S2MV_D) { r = idx - FB_S2MV_C; KS=8; KK=256; src=l1_w_s2mv; }
    else                      { r = idx - FB_S2MV_D; KS=8; KK=256; src=l2_w_s2mv; }
    const int per = KS*512, nt = r / per, r3 = r % per;
    const int ks = r3 >> 9, l = (r3 >> 3) & 63, e = r3 & 7;
    const int o = 16*nt + (l & 15), k = 32*ks + 8*(l >> 4) + e;
    v = src[o*KK + k];
  } else if (idx < FB_MS2S_B) {                // s2s  [N x K]
    const float* src; int r, KS, KK;
    if (idx < FB_S2S_C)      { r = idx - FB_S2S_B; KS=4; KK=128; src=gbo_w_s2s; }
    else if (idx < FB_S2S_D) { r = idx - FB_S2S_C; KS=8; KK=256; src=l1_w_s2s; }
    else                     { r = idx - FB_S2S_D; KS=8; KK=256; src=l2_w_s2s; }
    const int per = KS*512, nt = r / per, r3 = r % per;
    const int ks = r3 >> 9, l = (r3 >> 3) & 63, e = r3 & 7;
    const int o = 16*nt + (l & 15), k = 32*ks + 8*(l >> 4) + e;
    v = src[o*KK + k];
  } else {                                     // mvs2s [N x 64]
    const float* src; int r;
    if (idx < FB_MS2S_C)      { r = idx - FB_MS2S_B; src = gbo_w_mvs2s; }
    else if (idx < FB_MS2S_D) { r = idx - FB_MS2S_C; src = l1_w_mvs2s; }
    else                      { r = idx - FB_MS2S_D; src = l2_w_mvs2s; }
    const int nt = r >> 10, r3 = r & 1023;
    const int ks = r3 >> 9, l = (r3 >> 3) & 63, e = r3 & 7;
    const int o = 16*nt + (l & 15), k = 32*ks + 8*(l >> 4) + e;
    v = src[o*64 + k];
  }
  __bf16* WB = (__bf16*)WBu;
  const __bf16 h = (__bf16)v;
  WB[idx] = h;
  WB[TOT_BF + idx] = (__bf16)(v - (float)h);
}

// ======================= Kernel A (unchanged structure, new offsets) =======================
__global__ __launch_bounds__(256, 1) void stage_a(
    const float* __restrict__ xin, const float* __restrict__ sinp,
    const float* __restrict__ gb_b_mv, const float* __restrict__ W,
    float* __restrict__ hid)
{
  __shared__ float smem[16384];
  const int tid = threadIdx.x;
  const int n0  = blockIdx.x * 8;
  {
    const float4* src = (const float4*)(xin + (size_t)n0 * 1024);
    float4* dst = (float4*)smem;
    #pragma unroll
    for (int q = 0; q < 8; ++q) dst[q * 256 + tid] = src[q * 256 + tid];
    ((float4*)(smem + 8192))[tid] = ((const float4*)(sinp + (size_t)n0 * 128))[tid];
  }
  __syncthreads();
  const int r  = tid & 127;
  const int pg = tid >> 7;
  float acc[4][16];
  #pragma unroll
  for (int i = 0; i < 4; ++i)
    #pragma unroll
    for (int j = 0; j < 16; ++j) acc[i][j] = 0.0f;
  const float* Wg = W + OFF_GBW;
  const float* xp = smem + pg * 4096;
  for (int c = 0; c < 64; ++c) {
    const float4 wa = *(const float4*)(Wg + (((c*3+0)<<7) + r)*4);
    const float4 wb = *(const float4*)(Wg + (((c*3+1)<<7) + r)*4);
    const float4 wc = *(const float4*)(Wg + (((c*3+2)<<7) + r)*4);
    const float w12[12] = {wa.x,wa.y,wa.z,wa.w, wb.x,wb.y,wb.z,wb.w, wc.x,wc.y,wc.z,wc.w};
    #pragma unroll
    for (int i = 0; i < 4; ++i) {
      float xv[16];
      ld16(xp + i*1024 + c*16, xv);
      accum_equi(acc[i], w12, xv);
    }
  }
  {
    const float* Ws = W + OFF_GB_S2MV;
    const float* sp = smem + 8192 + pg * 512;
    for (int kq = 0; kq < 32; ++kq) {
      const float4 wq = *(const float4*)(Ws + ((kq<<7) + r)*4);
      #pragma unroll
      for (int i = 0; i < 4; ++i) {
        const float4 sv = *(const float4*)(sp + i*128 + (kq<<2));
        acc[i][0] += dot4(wq, sv);
      }
    }
    const float bias = gb_b_mv[r];
    #pragma unroll
    for (int i = 0; i < 4; ++i) acc[i][0] += bias;
  }
  __syncthreads();
  #pragma unroll
  for (int i = 0; i < 4; ++i)
    st16(smem + ((pg*4 + i)*128 + r)*16, acc[i]);
  __syncthreads();
  {
    const int h  = tid & 31;
    const int pp = tid >> 5;
    float L[16], R[16], o16[16];
    ld16(smem + (pp*128 + h)*16, L);
    ld16(smem + (pp*128 + 32 + h)*16, R);
    #pragma unroll
    for (int j = 0; j < 16; ++j) o16[j] = 0.0f;
    #pragma unroll
    for (int n = 0; n < 192; ++n)
      o16[ga::GPt.e[n].k] = fmaf(ga::GPt.e[n].s * L[ga::GPt.e[n].i], R[ga::GPt.e[n].j], o16[ga::GPt.e[n].k]);
    st16(hid + (((size_t)(n0 + pp) * 64) + h) * 16, o16);
    ld16(smem + (pp*128 + 64 + h)*16, L);
    ld16(smem + (pp*128 + 96 + h)*16, R);
    #pragma unroll
    for (int j = 0; j < 16; ++j) o16[j] = 0.0f;
    #pragma unroll
    for (int n = 0; n < 81; ++n)
      o16[ga::JNt.e[n].k] = fmaf(ga::JNt.e[n].s * L[ga::JNt.e[n].i], R[ga::JNt.e[n].j], o16[ga::JNt.e[n].k]);
    st16(hid + (((size_t)(n0 + pp) * 64) + 32 + h) * 16, o16);
  }
}

// ======================= bcdm device helpers =======================
// mv equi-linear as per-blade GEMMs: Y_j = X_j @ W_g(j) + [e0] X_pj @ W_ke(j).
__device__ __forceinline__ void mv_gemm(f32x4 (&acc)[16], const __bf16* __restrict__ WB,
                                        const unsigned char* lds, int mvbase, int w, int lane)
{
  constexpr int GR[16] = {0,1,1,1,1,2,2,2,2,2,2,3,3,3,3,4};
  constexpr int PJ[16] = {-1,0,-1,-1,-1,2,3,4,-1,-1,-1,8,9,10,-1,14};
  constexpr int KE[16] = {0,5,0,0,0,6,6,6,0,0,0,7,7,7,0,8};
  const int pa  = lane & 15;
  const int cb0 = (lane >> 4) << 4;
  const int wl8 = lane << 3;
  #pragma unroll
  for (int j = 0; j < 16; ++j) {
    #pragma unroll
    for (int ks = 0; ks < 2; ++ks) {
      bf16x8 a = *(const bf16x8*)(lds + XA_OFF + (((j<<4)+pa)<<7) + swz(pa, cb0 + (ks<<6)));
      const __bf16* bp = WB + mvbase + GR[j]*4096 + (w<<10) + (ks<<9) + wl8;
      acc[j] = __builtin_amdgcn_mfma_f32_16x16x32_bf16(a, *(const bf16x8*)bp, acc[j], 0, 0, 0);
      acc[j] = __builtin_amdgcn_mfma_f32_16x16x32_bf16(a, *(const bf16x8*)(bp + TOT_BF), acc[j], 0, 0, 0);
    }
    if (PJ[j] >= 0) {
      #pragma unroll
      for (int ks = 0; ks < 2; ++ks) {
        bf16x8 a = *(const bf16x8*)(lds + XA_OFF + (((PJ[j]<<4)+pa)<<7) + swz(pa, cb0 + (ks<<6)));
        const __bf16* bp = WB + mvbase + KE[j]*4096 + (w<<10) + (ks<<9) + wl8;
        acc[j] = __builtin_amdgcn_mfma_f32_16x16x32_bf16(a, *(const bf16x8*)bp, acc[j], 0, 0, 0);
        acc[j] = __builtin_amdgcn_mfma_f32_16x16x32_bf16(a, *(const bf16x8*)(bp + TOT_BF), acc[j], 0, 0, 0);
      }
    }
  }
}
// scalar GEMM: A from an LDS row buffer (rows 1<<RSH bytes, swizzled), K = 32*KS.
template<int KS, int RSH>
__device__ __forceinline__ void s_gemm(f32x4& acc, const __bf16* __restrict__ WB,
                                       const unsigned char* lds, int abase, int wbase, int lane)
{
  const int pa  = lane & 15;
  const int cb0 = (lane >> 4) << 4;
  const int wl8 = lane << 3;
  #pragma unroll
  for (int ks = 0; ks < KS; ++ks) {
    bf16x8 a = *(const bf16x8*)(lds + abase + (pa << RSH) + swz(pa, cb0 + (ks << 6)));
    const __bf16* bp = WB + wbase + (ks << 9) + wl8;
    acc = __builtin_amdgcn_mfma_f32_16x16x32_bf16(a, *(const bf16x8*)bp, acc, 0, 0, 0);
    acc = __builtin_amdgcn_mfma_f32_16x16x32_bf16(a, *(const bf16x8*)(bp + TOT_BF), acc, 0, 0, 0);
  }
}

// ======================= bcdm: MFMA B/C/D pipeline =======================
// 16 points/block, 4 waves; wave w = o-tile [16w,16w+16). D-frag: p=(l>>4)*4+r, o=16w+(l&15).
__global__ __launch_bounds__(256, 1) void bcdm(
    const float* __restrict__ sinp,
    const float* __restrict__ gbo_b_mv, const float* __restrict__ gbo_b_s,
    const float* __restrict__ l1_b_mv,  const float* __restrict__ l1_b_s,
    const float* __restrict__ l2_b_mv,  const float* __restrict__ l2_b_s,
    const unsigned short* __restrict__ WBu,
    float* __restrict__ out)
{
  __shared__ __align__(16) unsigned char lds[LDS_BYTES];
  const __bf16* WB = (const __bf16*)WBu;
  const int tid = threadIdx.x, lane = tid & 63, w = tid >> 6;
  const int pg = lane >> 4, ol = lane & 15;
  const int n0 = blockIdx.x * 16;

  { // stage hidden -> XA bf16 [j][p][c] swizzled, + C0, + SA (sinp)
    const float4* hsrc = (const float4*)(out + (size_t)n0 * 1024);
    #pragma unroll
    for (int q = 0; q < 16; ++q) {
      const int i = q * 256 + tid;
      const float4 v = hsrc[i];
      const int p = i >> 8, c = (i >> 2) & 63, j0 = (i & 3) << 2;
      const float vv[4] = {v.x, v.y, v.z, v.w};
      #pragma unroll
      for (int t = 0; t < 4; ++t)
        *(__bf16*)(lds + XA_OFF + ((((j0 + t) << 4) + p) << 7) + swz(p, 2 * c)) = (__bf16)vv[t];
      if (j0 == 0)
        *(__bf16*)(lds + C0_OFF + (p << 7) + swz(p, 2 * c)) = (__bf16)v.x;
    }
    const float4* ssrc = (const float4*)(sinp + (size_t)n0 * 128);
    #pragma unroll
    for (int q = 0; q < 2; ++q) {
      const int i = q * 256 + tid;
      const float4 v = ssrc[i];
      const int p = i >> 5, k0 = (i & 31) << 2;
      const float vv[4] = {v.x, v.y, v.z, v.w};
      #pragma unroll
      for (int t = 0; t < 4; ++t)
        *(__bf16*)(lds + SA_OFF + (p << 8) + swz(p, 2 * (k0 + t))) = (__bf16)vv[t];
    }
  }
  __syncthreads();

  float* REDEQ = (float*)(lds + RED_OFF);
  float* REDS  = REDEQ + 64;
  float* REDQ  = REDEQ + 128;

  // ================= stages B and C =================
  #pragma unroll 1
  for (int stage = 0; stage < 2; ++stage) {
    const int mvb   = stage == 0 ? FB_MVB    : FB_MVC;
    const int s2mvb = stage == 0 ? FB_S2MV_B : FB_S2MV_C;
    const int s2sb  = stage == 0 ? FB_S2S_B  : FB_S2S_C;
    const int ms2sb = stage == 0 ? FB_MS2S_B : FB_MS2S_C;
    const int sab   = stage == 0 ? SA_OFF    : T1_OFF;
    const int tdst  = stage == 0 ? T1_OFF    : T2_OFF;
    const float* b_mv = stage == 0 ? gbo_b_mv : l1_b_mv;
    const float* b_s  = stage == 0 ? gbo_b_s  : l1_b_s;

    f32x4 acc[16], fac[4];
    #pragma unroll
    for (int j = 0; j < 16; ++j) acc[j] = f32x4{0.f,0.f,0.f,0.f};
    #pragma unroll
    for (int t = 0; t < 4; ++t) fac[t] = f32x4{0.f,0.f,0.f,0.f};

    mv_gemm(acc, WB, lds, mvb, w, lane);
    if (stage == 0) {
      s_gemm<4,8>(acc[0], WB, lds, sab, s2mvb + w*2048, lane);
      #pragma unroll
      for (int nt2 = 0; nt2 < 4; ++nt2) {
        s_gemm<4,8>(fac[nt2], WB, lds, sab, s2sb + (4*w+nt2)*2048, lane);
        s_gemm<2,7>(fac[nt2], WB, lds, C0_OFF, ms2sb + (4*w+nt2)*1024, lane);
      }
    } else {
      s_gemm<8,9>(acc[0], WB, lds, sab, s2mvb + w*4096, lane);
      #pragma unroll
      for (int nt2 = 0; nt2 < 4; ++nt2) {
        s_gemm<8,9>(fac[nt2], WB, lds, sab, s2sb + (4*w+nt2)*4096, lane);
        s_gemm<2,7>(fac[nt2], WB, lds, C0_OFF, ms2sb + (4*w+nt2)*1024, lane);
      }
    }
    __syncthreads();                    // all this stage's LDS reads done

    // biases
    {
      const float bm = b_mv[16*w + ol];
      #pragma unroll
      for (int r = 0; r < 4; ++r) acc[0][r] += bm;
      #pragma unroll
      for (int nt2 = 0; nt2 < 4; ++nt2) {
        const float bs = b_s[16*(4*w+nt2) + ol];
        #pragma unroll
        for (int r = 0; r < 4; ++r) fac[nt2][r] += bs;
      }
    }
    // norm partials (INNER = {0,2,3,4,8,9,10,14})
    float sq[4], sm[4], s2[4];
    #pragma unroll
    for (int r = 0; r < 4; ++r) {
      sq[r] = acc[0][r]*acc[0][r] + acc[2][r]*acc[2][r] + acc[3][r]*acc[3][r] + acc[4][r]*acc[4][r]
            + acc[8][r]*acc[8][r] + acc[9][r]*acc[9][r] + acc[10][r]*acc[10][r] + acc[14][r]*acc[14][r];
      sm[r] = fac[0][r]+fac[1][r]+fac[2][r]+fac[3][r];
      s2[r] = fac[0][r]*fac[0][r]+fac[1][r]*fac[1][r]+fac[2][r]*fac[2][r]+fac[3][r]*fac[3][r];
    }
    #pragma unroll
    for (int m = 1; m < 16; m <<= 1) {
      #pragma unroll
      for (int r = 0; r < 4; ++r) {
        sq[r] += __shfl_xor(sq[r], m);
        sm[r] += __shfl_xor(sm[r], m);
        s2[r] += __shfl_xor(s2[r], m);
      }
    }
    if (ol == 0) {
      #pragma unroll
      for (int r = 0; r < 4; ++r) {
        const int p = pg*4 + r;
        REDEQ[w*16 + p] = sq[r]; REDS[w*16 + p] = sm[r]; REDQ[w*16 + p] = s2[r];
      }
    }
    __syncthreads();

    float rs[4], mu[4], rstd[4];
    #pragma unroll
    for (int r = 0; r < 4; ++r) {
      const int p = pg*4 + r;
      const float te = REDEQ[p] + REDEQ[16+p] + REDEQ[32+p] + REDEQ[48+p];
      rs[r] = 1.0f / sqrtf(fmaxf(te * (1.0f/64.0f), 0.01f));
      const float ts = REDS[p] + REDS[16+p] + REDS[32+p] + REDS[48+p];
      const float tq = REDQ[p] + REDQ[16+p] + REDQ[32+p] + REDQ[48+p];
      mu[r]   = ts * (1.0f/256.0f);
      rstd[r] = rsqrtf(tq * (1.0f/256.0f) - mu[r]*mu[r] + 1e-5f);
    }
    // scalar out -> T (bf16)
    #pragma unroll
    for (int nt2 = 0; nt2 < 4; ++nt2) {
      #pragma unroll
      for (int r = 0; r < 4; ++r) {
        const int p = pg*4 + r, op = 16*(4*w+nt2) + ol;
        *(__bf16*)(lds + tdst + (p << 9) + swz(p, 2*op)) =
            (__bf16)gelu_t((fac[nt2][r] - mu[r]) * rstd[r]);
      }
    }
    // gated mv -> XA + C0 (our o-tile is next stage's c-tile)
    float gate[4];
    #pragma unroll
    for (int r = 0; r < 4; ++r) gate[r] = gelu_t(acc[0][r] * rs[r]);
    const int cnew = 16*w + ol;
    #pragma unroll
    for (int j = 0; j < 16; ++j) {
      #pragma unroll
      for (int r = 0; r < 4; ++r) {
        const int p = pg*4 + r;
        const float v = acc[j][r] * rs[r] * gate[r];
        *(__bf16*)(lds + XA_OFF + (((j<<4)+p)<<7) + swz(p, 2*cnew)) = (__bf16)v;
        if (j == 0)
          *(__bf16*)(lds + C0_OFF + (p<<7) + swz(p, 2*cnew)) = (__bf16)v;
      }
    }
    __syncthreads();
  }

  // ================= stage D =================
  {
    f32x4 acc[16], fac2[2];
    #pragma unroll
    for (int j = 0; j < 16; ++j) acc[j] = f32x4{0.f,0.f,0.f,0.f};
    fac2[0] = f32x4{0.f,0.f,0.f,0.f}; fac2[1] = f32x4{0.f,0.f,0.f,0.f};

    mv_gemm(acc, WB, lds, FB_MVD, w, lane);
    s_gemm<8,9>(acc[0], WB, lds, T2_OFF, FB_S2MV_D + w*4096, lane);
    #pragma unroll
    for (int nt2 = 0; nt2 < 2; ++nt2) {
      s_gemm<8,9>(fac2[nt2], WB, lds, T2_OFF, FB_S2S_D + (2*w+nt2)*4096, lane);
      s_gemm<2,7>(fac2[nt2], WB, lds, C0_OFF, FB_MS2S_D + (2*w+nt2)*1024, lane);
    }
    const float bm = l2_b_mv[16*w + ol];
    #pragma unroll
    for (int r = 0; r < 4; ++r) acc[0][r] += bm;
    #pragma unroll
    for (int r = 0; r < 4; ++r) {
      const int p = pg*4 + r;
      float* dst = out + ((size_t)(n0 + p)*64 + 16*w + ol)*16;
      *(float4*)(dst+0)  = make_float4(acc[0][r],  acc[1][r],  acc[2][r],  acc[3][r]);
      *(float4*)(dst+4)  = make_float4(acc[4][r],  acc[5][r],  acc[6][r],  acc[7][r]);
      *(float4*)(dst+8)  = make_float4(acc[8][r],  acc[9][r],  acc[10][r], acc[11][r]);
      *(float4*)(dst+12) = make_float4(acc[12][r], acc[13][r], acc[14][r], acc[15][r]);
    }
    #pragma unroll
    for (int nt2 = 0; nt2 < 2; ++nt2) {
      const int od = 16*(2*w+nt2) + ol;
      const float bs = l2_b_s[od];
      #pragma unroll
      for (int r = 0; r < 4; ++r) {
        const int p = pg*4 + r;
        out[SOFF + (size_t)(n0 + p)*128 + od] = fac2[nt2][r] + bs;
      }
    }
  }
}

// ============================ host launch ============================
extern "C" void kernel_launch(void* const* d_in, const int* in_sizes, int n_in,
                              void* d_out, int out_size, void* d_ws, size_t ws_size,
                              hipStream_t stream) {
  const float* xin          = (const float*)d_in[0];
  const float* sinp         = (const float*)d_in[1];
  const float* gb_w_mv      = (const float*)d_in[2];
  const float* gb_w_s2mv    = (const float*)d_in[3];
  const float* gb_b_mv      = (const float*)d_in[4];
  const float* gbo_w_mv     = (const float*)d_in[5];
  const float* gbo_w_s2mv   = (const float*)d_in[6];
  const float* gbo_b_mv     = (const float*)d_in[7];
  const float* gbo_w_mvs2s  = (const float*)d_in[8];
  const float* gbo_w_s2s    = (const float*)d_in[9];
  const float* gbo_b_s      = (const float*)d_in[10];
  const float* l1_w_mv      = (const float*)d_in[11];
  const float* l1_w_s2mv    = (const float*)d_in[12];
  const float* l1_b_mv      = (const float*)d_in[13];
  const float* l1_w_mvs2s   = (const float*)d_in[14];
  const float* l1_w_s2s     = (const float*)d_in[15];
  const float* l1_b_s       = (const float*)d_in[16];
  const float* l2_w_mv      = (const float*)d_in[17];
  const float* l2_w_s2mv    = (const float*)d_in[18];
  const float* l2_b_mv      = (const float*)d_in[19];
  const float* l2_w_mvs2s   = (const float*)d_in[20];
  const float* l2_w_s2s     = (const float*)d_in[21];
  const float* l2_b_s       = (const float*)d_in[22];
  float* W   = (float*)d_ws;
  unsigned short* WBu = (unsigned short*)(W + FP_TOTAL);
  float* out = (float*)d_out;

  prep_fp<<<(FP_TOTAL + 255) / 256, 256, 0, stream>>>(gb_w_mv, gb_w_s2mv, W);

  prep_bf<<<(TOT_BF + 255) / 256, 256, 0, stream>>>(
      gbo_w_mv, gbo_w_s2mv, gbo_w_mvs2s, gbo_w_s2s,
      l1_w_mv, l1_w_s2mv, l1_w_mvs2s, l1_w_s2s,
      l2_w_mv, l2_w_s2mv, l2_w_mvs2s, l2_w_s2s, WBu);

  stage_a<<<NPTS / 8, 256, 0, stream>>>(xin, sinp, gb_b_mv, W, out);

  bcdm<<<NPTS / 16, 256, 0, stream>>>(
      sinp, gbo_b_mv, gbo_b_s, l1_b_mv, l1_b_s, l2_b_mv, l2_b_s, WBu, out);
}